// Round 10
// baseline (1585.205 us; speedup 1.0000x reference)
//
#include <hip/hip_runtime.h>
#include <math.h>

// Problem constants
#define NN 118   // nodes
#define EE 372   // edges
#define GG 2048  // B*T
#define DD 128   // hidden
#define TT 256   // seq len
#define BB 8     // batch
#define FD 512   // 4*D

// LDS stride for bf16 matrices (rows 16B-aligned, 2-way-max bank aliasing)
#define XS 136

typedef short bf16x8 __attribute__((ext_vector_type(8)));
typedef float f32x4  __attribute__((ext_vector_type(4)));
typedef _Float16 half8 __attribute__((ext_vector_type(8)));

__device__ __forceinline__ float frcp_(float x) { return __builtin_amdgcn_rcpf(x); }
__device__ __forceinline__ float sig_f(float x) { return frcp_(1.0f + __expf(-x)); }
__device__ __forceinline__ float tanh_f(float x) { return 1.0f - 2.0f * frcp_(__expf(2.0f * x) + 1.0f); }
__device__ __forceinline__ float silu_f(float x) { return x * frcp_(1.0f + __expf(-x)); }
__device__ __forceinline__ float siluf_(float x) { return x / (1.0f + expf(-x)); }

// Barrier draining only LDS ops (lgkmcnt), not vmcnt: global stores stay
// fire-and-forget, prefetch loads stay in flight. Safe: all cross-thread data
// flows through LDS (global->VGPR uses get compiler vmcnt waits).
__device__ __forceinline__ void bar_lds() {
    asm volatile("s_waitcnt lgkmcnt(0)\n\ts_barrier" ::: "memory");
}

__device__ __forceinline__ unsigned short f2bf(float x) {
    unsigned int u = __float_as_uint(x);
    unsigned int r = (u + 0x7fffu + ((u >> 16) & 1u)) >> 16;
    return (unsigned short)r;
}
__device__ __forceinline__ float bf2f(unsigned short b) {
    return __uint_as_float(((unsigned int)b) << 16);
}

// ---------------------------------------------------------------------------
// prep: dense normalized adjacency A -> bf16 128x128 (zero padded), fused
// LSTM biases in gate-INTERLEAVED order p = 4d+g. 1 block.
// ---------------------------------------------------------------------------
__global__ void prep_kernel(const int* __restrict__ ei,
                            const float* __restrict__ bih0, const float* __restrict__ bhh0,
                            const float* __restrict__ bih1, const float* __restrict__ bhh1,
                            float* __restrict__ bias0, float* __restrict__ bias1,
                            unsigned short* __restrict__ AbG) {
    __shared__ int sflag;
    __shared__ int ssrc[EE], sdst[EE];
    __shared__ int scount[NN];
    __shared__ float sinv[NN];
    __shared__ float Adense[NN * NN];  // 55.7 KB
    int tid = threadIdx.x;
    if (tid == 0) sflag = 0;
    __syncthreads();
    // int64-vs-int32 layout detect (values < 118 -> high words zero if int64)
    for (int i = tid; i < 2 * EE; i += blockDim.x)
        if ((i & 1) && ei[i] != 0) atomicOr(&sflag, 1);
    __syncthreads();
    bool m64 = (sflag == 0);
    for (int e = tid; e < EE; e += blockDim.x) {
        int s, d;
        if (m64) { s = ei[2 * e]; d = ei[2 * EE + 2 * e]; }
        else     { s = ei[e];     d = ei[EE + e]; }
        s = min(max(s, 0), NN - 1); d = min(max(d, 0), NN - 1);
        ssrc[e] = s; sdst[e] = d;
    }
    for (int n = tid; n < NN; n += blockDim.x) scount[n] = 0;
    for (int i = tid; i < NN * NN; i += blockDim.x) Adense[i] = 0.0f;
    __syncthreads();
    for (int e = tid; e < EE; e += blockDim.x) atomicAdd(&scount[sdst[e]], 1);
    __syncthreads();
    for (int n = tid; n < NN; n += blockDim.x) {
        float deg = 1.0f + (float)scount[n];
        sinv[n] = rsqrtf(deg);
        Adense[n * NN + n] = 1.0f / deg;   // self term h*(1/deg)
    }
    __syncthreads();
    for (int e = tid; e < EE; e += blockDim.x)
        atomicAdd(&Adense[sdst[e] * NN + ssrc[e]], sinv[ssrc[e]] * sinv[sdst[e]]);
    __syncthreads();
    for (int i = tid; i < 128 * 128; i += blockDim.x) {
        int r = i >> 7, c = i & 127;
        AbG[i] = (r < NN && c < NN) ? f2bf(Adense[r * NN + c]) : (unsigned short)0;
    }
    for (int p = tid; p < FD; p += blockDim.x) {
        int jp = (p & 3) * 128 + (p >> 2);   // interleaved -> original gate index
        bias0[p] = bih0[jp] + bhh0[jp];
        bias1[p] = bih1[jp] + bhh1[jp];
    }
}

// ---------------------------------------------------------------------------
// W (K=128 x N=128, fp32) -> bf16 [n][k] (k contiguous) for MFMA B-frags
// ---------------------------------------------------------------------------
__global__ void convw_kernel(const float* __restrict__ W, unsigned short* __restrict__ out) {
    int i = blockIdx.x * 512 + threadIdx.x;  // 16384 total
    int n = i >> 7, k = i & 127;
    out[i] = f2bf(W[k * DD + n]);
}

// ---------------------------------------------------------------------------
// Whh (512x128 fp32, rows j=g*128+d) -> f16 [512][128], rows r=4d+g
// (gate-interleaved for MFMA lane-local cell update)
// ---------------------------------------------------------------------------
__global__ void convwhh_kernel(const float* __restrict__ W, unsigned short* __restrict__ out) {
    int i = blockIdx.x * 512 + threadIdx.x;  // 65536 total
    int r = i >> 7, k = i & 127;
    int j = (r & 3) * 128 + (r >> 2);
    _Float16 v = (_Float16)W[j * 128 + k];
    out[i] = __builtin_bit_cast(unsigned short, v);
}

// ---------------------------------------------------------------------------
// Wih (512x128, rows j) -> WTi [k=128][p=512] with p = 4d+g interleaving,
// so proj writes (and scan reads) gates in interleaved order, coalesced.
// ---------------------------------------------------------------------------
__global__ void transpose_kernel(const float* __restrict__ in, float* __restrict__ out) {
    int idx = blockIdx.x * blockDim.x + threadIdx.x;  // 65536 total
    int k = idx >> 9, p = idx & 511;
    int jp = (p & 3) * 128 + (p >> 2);
    out[idx] = in[jp * 128 + k];
}

// ---------------------------------------------------------------------------
// GCN building blocks (unchanged since round 5)
// ---------------------------------------------------------------------------
__device__ __forceinline__ void load_m(const unsigned short* __restrict__ src,
                                       unsigned short* __restrict__ dst, int tid) {
    const uint4* s4 = (const uint4*)src;  // 2048 chunks of 16B (8 bf16)
    for (int c = tid; c < 2048; c += 512) {
        int r = c >> 4, k8 = (c & 15) * 8;
        uint4 v = s4[c];
        *(uint4*)(dst + r * XS + k8) = v;
    }
}

// mm1: hS[n=dout][m=node] = (xb[m][k] @ wt[n][k]) packed bf16
__device__ __forceinline__ void mm_xw(const unsigned short* __restrict__ xb,
                                      const unsigned short* __restrict__ wt,
                                      unsigned short* __restrict__ hS, int tid) {
    int lane = tid & 63, w = tid >> 6;
    int lm = lane & 15, lq = lane >> 4;
    int wm = (w & 1) * 64, wn = (w >> 1) * 32;
    f32x4 acc[4][2];
#pragma unroll
    for (int mt = 0; mt < 4; ++mt)
#pragma unroll
        for (int nt = 0; nt < 2; ++nt) acc[mt][nt] = (f32x4){0.f, 0.f, 0.f, 0.f};
#pragma unroll
    for (int kb = 0; kb < 4; ++kb) {
        int ko = kb * 32 + lq * 8;
        bf16x8 b0 = *(const bf16x8*)(wt + (wn + lm) * XS + ko);
        bf16x8 b1 = *(const bf16x8*)(wt + (wn + 16 + lm) * XS + ko);
#pragma unroll
        for (int mt = 0; mt < 4; ++mt) {
            bf16x8 af = *(const bf16x8*)(xb + (wm + mt * 16 + lm) * XS + ko);
            acc[mt][0] = __builtin_amdgcn_mfma_f32_16x16x32_bf16(af, b0, acc[mt][0], 0, 0, 0);
            acc[mt][1] = __builtin_amdgcn_mfma_f32_16x16x32_bf16(af, b1, acc[mt][1], 0, 0, 0);
        }
    }
#pragma unroll
    for (int mt = 0; mt < 4; ++mt)
#pragma unroll
        for (int nt = 0; nt < 2; ++nt) {
            f32x4 a = acc[mt][nt];
            ushort4 pk;
            pk.x = f2bf(a[0]); pk.y = f2bf(a[1]); pk.z = f2bf(a[2]); pk.w = f2bf(a[3]);
            *(ushort4*)(hS + (wn + nt * 16 + lm) * XS + wm + mt * 16 + lq * 4) = pk;
        }
}

// mm2: xb[m=node][n=d] = silu(Ab[m][k] @ hS[n][k] + bias[n]) bf16
__device__ __forceinline__ void mm_agg(const unsigned short* __restrict__ Ab,
                                       const unsigned short* __restrict__ hS,
                                       unsigned short* __restrict__ xb,
                                       float bn0, float bn1, int tid) {
    int lane = tid & 63, w = tid >> 6;
    int lm = lane & 15, lq = lane >> 4;
    int wm = (w & 1) * 64, wn = (w >> 1) * 32;
    f32x4 acc[4][2];
#pragma unroll
    for (int mt = 0; mt < 4; ++mt)
#pragma unroll
        for (int nt = 0; nt < 2; ++nt) acc[mt][nt] = (f32x4){0.f, 0.f, 0.f, 0.f};
#pragma unroll
    for (int kb = 0; kb < 4; ++kb) {
        int ko = kb * 32 + lq * 8;
        bf16x8 b0 = *(const bf16x8*)(hS + (wn + lm) * XS + ko);
        bf16x8 b1 = *(const bf16x8*)(hS + (wn + 16 + lm) * XS + ko);
#pragma unroll
        for (int mt = 0; mt < 4; ++mt) {
            bf16x8 af = *(const bf16x8*)(Ab + (wm + mt * 16 + lm) * XS + ko);
            acc[mt][0] = __builtin_amdgcn_mfma_f32_16x16x32_bf16(af, b0, acc[mt][0], 0, 0, 0);
            acc[mt][1] = __builtin_amdgcn_mfma_f32_16x16x32_bf16(af, b1, acc[mt][1], 0, 0, 0);
        }
    }
#pragma unroll
    for (int mt = 0; mt < 4; ++mt)
#pragma unroll
        for (int nt = 0; nt < 2; ++nt) {
            float bn = nt ? bn1 : bn0;
            int col = wn + nt * 16 + lm;
#pragma unroll
            for (int i = 0; i < 4; ++i) {
                float v = silu_f(acc[mt][nt][i] + bn);
                xb[(wm + mt * 16 + lq * 4 + i) * XS + col] = f2bf(v);
            }
        }
}

__global__ __launch_bounds__(512) void gcn_kernel(
    const float* __restrict__ xg, const float* __restrict__ scale, const float* __restrict__ shift,
    const float* __restrict__ W1, const float* __restrict__ b1,
    const float* __restrict__ b2, const float* __restrict__ b3,
    const unsigned short* __restrict__ AbG,
    const unsigned short* __restrict__ Wt2g, const unsigned short* __restrict__ Wt3g,
    float* __restrict__ emb) {
    extern __shared__ char smem[];
    unsigned short* xb = (unsigned short*)smem;              // 34816 B  [node][d]
    unsigned short* hS = (unsigned short*)(smem + 34816);    // 34816 B  [d][node]
    unsigned short* Ab = (unsigned short*)(smem + 69632);    // 34816 B  [dst][src]
    unsigned short* wt = (unsigned short*)(smem + 104448);   // 34816 B  [dout][din]
    float* xinL  = (float*)(smem + 139264);                  // 354 f
    float* meanS = (float*)(smem + 140688);                  // 512 f (end 142736)
    int tid = threadIdx.x;
    int lane = tid & 63, w = tid >> 6;
    int g = blockIdx.x;

    for (int i = tid; i < 2176; i += 512) ((uint4*)hS)[i] = (uint4){0, 0, 0, 0};
    for (int i = tid; i < 170; i += 512) ((uint4*)(xb + NN * XS))[i] = (uint4){0, 0, 0, 0};
    float s0 = scale[0], s1 = scale[1], s2 = scale[2];
    float t0 = shift[0], t1 = shift[1], t2 = shift[2];
    const float* xrow = xg + (size_t)g * (NN * 3);
    for (int i = tid; i < NN * 3; i += 512) {
        int f = i % 3;
        float sc = (f == 0) ? s0 : ((f == 1) ? s1 : s2);
        float sf = (f == 0) ? t0 : ((f == 1) ? t1 : t2);
        xinL[i] = xrow[i] * sc + sf;
    }
    load_m(AbG, Ab, tid);
    load_m(Wt2g, wt, tid);
    int lm = lane & 15;
    int wn = (w >> 1) * 32;
    int n0 = wn + lm, n1 = wn + 16 + lm;
    float b1a = b1[n0], b1b = b1[n1];
    float b2a = b2[n0], b2b = b2[n1];
    float b3a = b3[n0], b3b = b3[n1];
    int dd = lane * 2;
    float2 w10 = *(const float2*)(W1 + dd);
    float2 w11 = *(const float2*)(W1 + DD + dd);
    float2 w12 = *(const float2*)(W1 + 2 * DD + dd);
    bar_lds();
    for (int k = 0; k < 15; ++k) {
        int n = w + 8 * k;
        if (n >= NN) break;
        float x0 = xinL[n * 3], x1 = xinL[n * 3 + 1], x2 = xinL[n * 3 + 2];
        hS[dd * XS + n]       = f2bf(x0 * w10.x + x1 * w11.x + x2 * w12.x);
        hS[(dd + 1) * XS + n] = f2bf(x0 * w10.y + x1 * w11.y + x2 * w12.y);
    }
    bar_lds();
    mm_agg(Ab, hS, xb, b1a, b1b, tid);   // x1
    bar_lds();
    mm_xw(xb, wt, hS, tid);              // h2
    bar_lds();
    load_m(Wt3g, wt, tid);
    mm_agg(Ab, hS, xb, b2a, b2b, tid);   // x2
    bar_lds();
    mm_xw(xb, wt, hS, tid);              // h3
    bar_lds();
    mm_agg(Ab, hS, xb, b3a, b3b, tid);   // x3
    bar_lds();
    {
        int d = tid & 127, part = tid >> 7;
        int a0 = part * 30;
        int a1 = (a0 + 30 < NN) ? (a0 + 30) : NN;
        float s = 0.f;
        for (int n = a0; n < a1; ++n) s += bf2f(xb[n * XS + d]);
        meanS[part * 128 + d] = s;
    }
    bar_lds();
    if (tid < 128) {
        float s = meanS[tid] + meanS[128 + tid] + meanS[256 + tid] + meanS[384 + tid];
        emb[(size_t)g * DD + tid] = s * (1.0f / (float)NN);
    }
}

// ---------------------------------------------------------------------------
// proj: dst[g][p] = bias[p] + sum_k src[g][k] * WTi[k][p]  (interleaved p)
// ---------------------------------------------------------------------------
__global__ __launch_bounds__(512) void proj_kernel(const float* __restrict__ src,
                                                   const float* __restrict__ WT,
                                                   const float* __restrict__ bias,
                                                   float* __restrict__ dst) {
    __shared__ __align__(16) float eL[DD];
    int g = blockIdx.x, tid = threadIdx.x;
    if (tid < DD) eL[tid] = src[(size_t)g * DD + tid];
    __syncthreads();
    float acc = bias[tid];
    const float* wt = WT + tid;
#pragma unroll 8
    for (int k = 0; k < DD; ++k) acc += eL[k] * wt[(size_t)k * FD];
    dst[(size_t)g * FD + tid] = acc;
}

// ---------------------------------------------------------------------------
// LSTM scan via MFMA, one block per batch element (round-7 structure +
// round-8/9 asm-pin fix). Whhi rows r=4d+g: C-frag layout (col=lane&15,
// row=lq*4+reg) puts i,f,g,o of dim d in the 4 acc regs of ONE lane ->
// cell update lane-local, c in 4 VGPRs for all 256 steps.
// A-frags = 16 x uint4 = 64 regs, ASM-PINNED (round-7 failure: compiler
// rematerialized the loads into the loop, VGPR_Count=56, ~6200 cyc/step).
// MFMA reads A from AGPRs natively, so even AGPR parking is free here.
// B = h (f16) in LDS, double-buffered; only lanes lm==0 carry data (N-col 0).
// Per step: 4 masked ds_read_b128 + 16 MFMA + lane-local epilogue + 1 barrier.
// ---------------------------------------------------------------------------
#define HP 136  // h buffer pad (f16 elems)
__global__ __launch_bounds__(512, 2) void scan_kernel(
    const float* __restrict__ inp,            // [B][T][512] interleaved p=4d+g (bias incl)
    const unsigned short* __restrict__ Whhi,  // [512][128] f16, rows r=4d+g
    float* __restrict__ hout, int full) {
    __shared__ unsigned short hL[2][HP];
    int b = blockIdx.x, tid = threadIdx.x;
    int lane = tid & 63, w = tid >> 6;
    int lm = lane & 15, lq = lane >> 4;
    // zero both h buffers (h_{-1} = 0)
    for (int i = tid; i < HP; i += 512) ((unsigned int*)hL)[i] = 0u;
    // A-frags: rows w*64 + mt*16 + lm, cols kb*32 + lq*8 (+0..7)
    uint4 afr[4][4];
#pragma unroll
    for (int mt = 0; mt < 4; ++mt)
#pragma unroll
        for (int kb = 0; kb < 4; ++kb)
            afr[mt][kb] = *(const uint4*)(Whhi + (w * 64 + mt * 16 + lm) * 128 + kb * 32 + lq * 8);
    // pin: asm-defined values cannot be rematerialized into the loop
#pragma unroll
    for (int mt = 0; mt < 4; ++mt)
#pragma unroll
        for (int kb = 0; kb < 4; ++kb)
            asm volatile("" : "+v"(afr[mt][kb].x), "+v"(afr[mt][kb].y),
                              "+v"(afr[mt][kb].z), "+v"(afr[mt][kb].w));
    const float* ib = inp + (size_t)b * TT * FD;
    float* hb_ = hout + (size_t)b * (full ? TT * DD : DD);
    int xcol = w * 64 + lq * 4;  // +mt*16
    float4 xq[2][4];
#pragma unroll
    for (int mt = 0; mt < 4; ++mt) {
        xq[0][mt] = *(const float4*)(ib + 0 * FD + xcol + mt * 16);
        xq[1][mt] = *(const float4*)(ib + 1 * FD + xcol + mt * 16);
    }
    float creg[4] = {0.f, 0.f, 0.f, 0.f};
    bar_lds();
    for (int t = 0; t < TT; ++t) {
        const unsigned short* hcur = hL[t & 1];
        _Float16* hnxt = (_Float16*)hL[(t + 1) & 1];
        uint4 bfr[4] = {{0,0,0,0},{0,0,0,0},{0,0,0,0},{0,0,0,0}};
        if (lm == 0) {   // only N-col 0 carries data; 4 lanes/wave, conflict-free
#pragma unroll
            for (int kb = 0; kb < 4; ++kb)
                bfr[kb] = *(const uint4*)(hcur + kb * 32 + lq * 8);
        }
        f32x4 acc[4];
#pragma unroll
        for (int mt = 0; mt < 4; ++mt) acc[mt] = (f32x4){0.f, 0.f, 0.f, 0.f};
#pragma unroll
        for (int kb = 0; kb < 4; ++kb) {
            half8 bv = __builtin_bit_cast(half8, bfr[kb]);
#pragma unroll
            for (int mt = 0; mt < 4; ++mt)
                acc[mt] = __builtin_amdgcn_mfma_f32_16x16x32_f16(
                    __builtin_bit_cast(half8, afr[mt][kb]), bv, acc[mt], 0, 0, 0);
        }
        int cur = t & 1;
        bool more = (t + 2 < TT);
#pragma unroll
        for (int mt = 0; mt < 4; ++mt) {
            float4 xg = xq[cur][mt];
            xq[cur][mt] = more ? *(const float4*)(ib + (t + 2) * FD + xcol + mt * 16)
                               : make_float4(0.f, 0.f, 0.f, 0.f);
            float iv = sig_f(acc[mt][0] + xg.x);
            float fv = sig_f(acc[mt][1] + xg.y);
            float gv = tanh_f(acc[mt][2] + xg.z);
            float ov = sig_f(acc[mt][3] + xg.w);
            float cn = fv * creg[mt] + iv * gv;
            creg[mt] = cn;
            float hn = ov * tanh_f(cn);
            int d = w * 16 + mt * 4 + lq;
            if (lm == 0) {
                hnxt[d] = (_Float16)hn;
                if (full) hb_[t * DD + d] = hn;            // fire-and-forget
                else if (t == TT - 1) hb_[d] = hn;
            }
        }
        bar_lds();
    }
}

// ---------------------------------------------------------------------------
// head MLP on final hidden state. 1 block.
// ---------------------------------------------------------------------------
__global__ void head_kernel(const float* __restrict__ hfin,
                            const float* __restrict__ hW1, const float* __restrict__ hb1,
                            const float* __restrict__ hW2, const float* __restrict__ hb2,
                            const float* __restrict__ hW3, const float* __restrict__ hb3,
                            float* __restrict__ out) {
    __shared__ float fh[BB * DD];
    __shared__ float y1[BB * DD];
    __shared__ float y2[BB * 64];
    int tid = threadIdx.x;
    for (int i = tid; i < BB * DD; i += 256) fh[i] = hfin[i];
    __syncthreads();
    for (int i = tid; i < BB * DD; i += 256) {
        int bb = i >> 7, jj = i & 127;
        float acc = hb1[jj];
        for (int k = 0; k < DD; ++k) acc += fh[(bb << 7) + k] * hW1[(k << 7) + jj];
        y1[i] = siluf_(acc);
    }
    __syncthreads();
    for (int i = tid; i < BB * 64; i += 256) {
        int bb = i >> 6, jj = i & 63;
        float acc = hb2[jj];
        for (int k = 0; k < DD; ++k) acc += y1[(bb << 7) + k] * hW2[(k << 6) + jj];
        y2[i] = siluf_(acc);
    }
    __syncthreads();
    if (tid < BB * 2) {
        int bb = tid >> 1, m = tid & 1;
        float acc = hb3[m];
        for (int k = 0; k < 64; ++k) acc += y2[(bb << 6) + k] * hW3[k * 2 + m];
        float sp = fmaxf(acc, 0.f) + log1pf(expf(-fabsf(acc)));
        out[tid] = sp + 1e-6f;
    }
}

// ---------------------------------------------------------------------------
extern "C" void kernel_launch(void* const* d_in, const int* in_sizes, int n_in,
                              void* d_out, int out_size, void* d_ws, size_t ws_size,
                              hipStream_t stream) {
    const float* snap  = (const float*)d_in[0];
    const int*   edges = (const int*)d_in[1];
    const float* scale = (const float*)d_in[2];
    const float* shift = (const float*)d_in[3];
    const float* W1 = (const float*)d_in[4];
    const float* b1 = (const float*)d_in[5];
    const float* W2 = (const float*)d_in[6];
    const float* b2 = (const float*)d_in[7];
    const float* W3 = (const float*)d_in[8];
    const float* b3 = (const float*)d_in[9];
    const float* Wih0 = (const float*)d_in[10];
    const float* Whh0 = (const float*)d_in[11];
    const float* bih0 = (const float*)d_in[12];
    const float* bhh0 = (const float*)d_in[13];
    const float* Wih1 = (const float*)d_in[14];
    const float* Whh1 = (const float*)d_in[15];
    const float* bih1 = (const float*)d_in[16];
    const float* bhh1 = (const float*)d_in[17];
    const float* hW1 = (const float*)d_in[18];
    const float* hb1 = (const float*)d_in[19];
    const float* hW2 = (const float*)d_in[20];
    const float* hb2 = (const float*)d_in[21];
    const float* hW3 = (const float*)d_in[22];
    const float* hb3 = (const float*)d_in[23];

    // workspace carve (float indices); ~7.2 MB
    float* ws = (float*)d_ws;
    float* bias0 = ws + 0;                        // 512 (interleaved)
    float* bias1 = ws + 512;                      // 512 (interleaved)
    unsigned short* AbG  = (unsigned short*)(ws + 1024);   // 8192 f
    unsigned short* Wt2g = (unsigned short*)(ws + 9216);   // 8192 f
    unsigned short* Wt3g = (unsigned short*)(ws + 17408);  // 8192 f
    float* WTi0 = ws + 25600;                     // 65536 (interleaved cols)
    float* WTi1 = ws + 91136;                     // 65536
    unsigned short* Whhi0 = (unsigned short*)(ws + 156672);  // 32768 f
    unsigned short* Whhi1 = (unsigned short*)(ws + 189440);  // 32768 f
    float* emb   = ws + 222208;                   // 262144
    float* inp   = ws + 484352;                   // 1048576 (both LSTM layers)
    float* h0seq = ws + 1532928;                  // 262144
    float* hfin  = ws + 1795072;                  // 1024

    const int smem_gcn = 142736;
    hipFuncSetAttribute((const void*)gcn_kernel,
                        hipFuncAttributeMaxDynamicSharedMemorySize, smem_gcn);

    prep_kernel<<<1, 256, 0, stream>>>(edges, bih0, bhh0, bih1, bhh1,
                                       bias0, bias1, AbG);
    convw_kernel<<<32, 512, 0, stream>>>(W2, Wt2g);
    convw_kernel<<<32, 512, 0, stream>>>(W3, Wt3g);
    convwhh_kernel<<<128, 512, 0, stream>>>(Whh0, Whhi0);
    convwhh_kernel<<<128, 512, 0, stream>>>(Whh1, Whhi1);
    transpose_kernel<<<128, 512, 0, stream>>>(Wih0, WTi0);
    transpose_kernel<<<128, 512, 0, stream>>>(Wih1, WTi1);
    gcn_kernel<<<GG, 512, smem_gcn, stream>>>(snap, scale, shift, W1, b1, b2, b3,
                                              AbG, Wt2g, Wt3g, emb);
    proj_kernel<<<GG, 512, 0, stream>>>(emb, WTi0, bias0, inp);
    scan_kernel<<<BB, 512, 0, stream>>>(inp, Whhi0, h0seq, 1);
    proj_kernel<<<GG, 512, 0, stream>>>(h0seq, WTi1, bias1, inp);
    scan_kernel<<<BB, 512, 0, stream>>>(inp, Whhi1, hfin, 0);
    head_kernel<<<1, 256, 0, stream>>>(hfin, hW1, hb1, hW2, hb2, hW3, hb3, (float*)d_out);
}

// Round 11
// 582.008 us; speedup vs baseline: 2.7237x; 2.7237x over previous
//
#include <hip/hip_runtime.h>
#include <math.h>

// Problem constants
#define NN 118   // nodes
#define EE 372   // edges
#define GG 2048  // B*T
#define DD 128   // hidden
#define TT 256   // seq len
#define BB 8     // batch
#define FD 512   // 4*D

// LDS stride for bf16 matrices (rows 16B-aligned, 2-way-max bank aliasing)
#define XS 136

typedef short bf16x8 __attribute__((ext_vector_type(8)));
typedef float f32x4  __attribute__((ext_vector_type(4)));
typedef _Float16 f16x2 __attribute__((ext_vector_type(2)));

__device__ __forceinline__ float frcp_(float x) { return __builtin_amdgcn_rcpf(x); }
__device__ __forceinline__ float sig_f(float x) { return frcp_(1.0f + __expf(-x)); }
__device__ __forceinline__ float tanh_f(float x) { return 1.0f - 2.0f * frcp_(__expf(2.0f * x) + 1.0f); }
__device__ __forceinline__ float silu_f(float x) { return x * frcp_(1.0f + __expf(-x)); }
__device__ __forceinline__ float siluf_(float x) { return x / (1.0f + expf(-x)); }

// f16-pair dot with fp32 accumulate (v_dot2_f32_f16); scalar fallback.
__device__ __forceinline__ float fdot2_(unsigned int a, unsigned int b, float c) {
#if defined(__has_builtin) && __has_builtin(__builtin_amdgcn_fdot2)
    return __builtin_amdgcn_fdot2(__builtin_bit_cast(f16x2, a),
                                  __builtin_bit_cast(f16x2, b), c, false);
#else
    f16x2 x = __builtin_bit_cast(f16x2, a), y = __builtin_bit_cast(f16x2, b);
    return c + (float)x[0] * (float)y[0] + (float)x[1] * (float)y[1];
#endif
}

// Barrier draining only LDS ops (lgkmcnt), not vmcnt: global stores stay
// fire-and-forget, prefetch loads stay in flight. Safe: all cross-thread data
// flows through LDS (global->VGPR uses get compiler vmcnt waits).
__device__ __forceinline__ void bar_lds() {
    asm volatile("s_waitcnt lgkmcnt(0)\n\ts_barrier" ::: "memory");
}

__device__ __forceinline__ unsigned short f2bf(float x) {
    unsigned int u = __float_as_uint(x);
    unsigned int r = (u + 0x7fffu + ((u >> 16) & 1u)) >> 16;
    return (unsigned short)r;
}
__device__ __forceinline__ float bf2f(unsigned short b) {
    return __uint_as_float(((unsigned int)b) << 16);
}

// ---------------------------------------------------------------------------
// prep: dense normalized adjacency A -> bf16 128x128 (zero padded), fused
// LSTM biases (plain gate-major order). 1 block.
// ---------------------------------------------------------------------------
__global__ void prep_kernel(const int* __restrict__ ei,
                            const float* __restrict__ bih0, const float* __restrict__ bhh0,
                            const float* __restrict__ bih1, const float* __restrict__ bhh1,
                            float* __restrict__ bias0, float* __restrict__ bias1,
                            unsigned short* __restrict__ AbG) {
    __shared__ int sflag;
    __shared__ int ssrc[EE], sdst[EE];
    __shared__ int scount[NN];
    __shared__ float sinv[NN];
    __shared__ float Adense[NN * NN];  // 55.7 KB
    int tid = threadIdx.x;
    if (tid == 0) sflag = 0;
    __syncthreads();
    // int64-vs-int32 layout detect (values < 118 -> high words zero if int64)
    for (int i = tid; i < 2 * EE; i += blockDim.x)
        if ((i & 1) && ei[i] != 0) atomicOr(&sflag, 1);
    __syncthreads();
    bool m64 = (sflag == 0);
    for (int e = tid; e < EE; e += blockDim.x) {
        int s, d;
        if (m64) { s = ei[2 * e]; d = ei[2 * EE + 2 * e]; }
        else     { s = ei[e];     d = ei[EE + e]; }
        s = min(max(s, 0), NN - 1); d = min(max(d, 0), NN - 1);
        ssrc[e] = s; sdst[e] = d;
    }
    for (int n = tid; n < NN; n += blockDim.x) scount[n] = 0;
    for (int i = tid; i < NN * NN; i += blockDim.x) Adense[i] = 0.0f;
    __syncthreads();
    for (int e = tid; e < EE; e += blockDim.x) atomicAdd(&scount[sdst[e]], 1);
    __syncthreads();
    for (int n = tid; n < NN; n += blockDim.x) {
        float deg = 1.0f + (float)scount[n];
        sinv[n] = rsqrtf(deg);
        Adense[n * NN + n] = 1.0f / deg;   // self term h*(1/deg)
    }
    __syncthreads();
    for (int e = tid; e < EE; e += blockDim.x)
        atomicAdd(&Adense[sdst[e] * NN + ssrc[e]], sinv[ssrc[e]] * sinv[sdst[e]]);
    __syncthreads();
    for (int i = tid; i < 128 * 128; i += blockDim.x) {
        int r = i >> 7, c = i & 127;
        AbG[i] = (r < NN && c < NN) ? f2bf(Adense[r * NN + c]) : (unsigned short)0;
    }
    for (int j = tid; j < FD; j += blockDim.x) {
        bias0[j] = bih0[j] + bhh0[j];
        bias1[j] = bih1[j] + bhh1[j];
    }
}

// ---------------------------------------------------------------------------
// W (K=128 x N=128, fp32) -> bf16 [n][k] (k contiguous) for MFMA B-frags
// ---------------------------------------------------------------------------
__global__ void convw_kernel(const float* __restrict__ W, unsigned short* __restrict__ out) {
    int i = blockIdx.x * 512 + threadIdx.x;  // 16384 total
    int n = i >> 7, k = i & 127;
    out[i] = f2bf(W[k * DD + n]);
}

// ---------------------------------------------------------------------------
// Whh (512x128 fp32, rows j=g*128+d) -> f16 pairs for the K-split-4 scan:
// out[(((g*16+q)*4)+quarter)*128 + d] = pack(W[g*128+d][32*quarter+2q], [+2q+1])
// Thread (quarter,d) loads (g,q) with consecutive-d coalescing.
// ---------------------------------------------------------------------------
__global__ void convh_kernel(const float* __restrict__ W, unsigned int* __restrict__ out) {
    int i = blockIdx.x * 512 + threadIdx.x;  // 32768 total
    int d = i & 127;
    int rest = i >> 7;          // 0..255
    int quarter = rest & 3;
    int qg = rest >> 2;         // 0..63
    int q = qg & 15, g = qg >> 4;
    const float* row = W + (size_t)(g * 128 + d) * 128 + quarter * 32;
    float a = row[2 * q], b = row[2 * q + 1];
    unsigned short lo = __builtin_bit_cast(unsigned short, (_Float16)a);
    unsigned short hi = __builtin_bit_cast(unsigned short, (_Float16)b);
    out[i] = (unsigned int)lo | ((unsigned int)hi << 16);
}

// ---------------------------------------------------------------------------
// Wih (512x128) -> WT [k=128][j=512] so proj reads coalesced
// ---------------------------------------------------------------------------
__global__ void transpose_kernel(const float* __restrict__ in, float* __restrict__ out) {
    int idx = blockIdx.x * blockDim.x + threadIdx.x;  // 65536 total
    int j = idx >> 7, k = idx & 127;
    out[k * FD + j] = in[idx];
}

// ---------------------------------------------------------------------------
// GCN building blocks (unchanged since round 5)
// ---------------------------------------------------------------------------
__device__ __forceinline__ void load_m(const unsigned short* __restrict__ src,
                                       unsigned short* __restrict__ dst, int tid) {
    const uint4* s4 = (const uint4*)src;  // 2048 chunks of 16B (8 bf16)
    for (int c = tid; c < 2048; c += 512) {
        int r = c >> 4, k8 = (c & 15) * 8;
        uint4 v = s4[c];
        *(uint4*)(dst + r * XS + k8) = v;
    }
}

// mm1: hS[n=dout][m=node] = (xb[m][k] @ wt[n][k]) packed bf16
__device__ __forceinline__ void mm_xw(const unsigned short* __restrict__ xb,
                                      const unsigned short* __restrict__ wt,
                                      unsigned short* __restrict__ hS, int tid) {
    int lane = tid & 63, w = tid >> 6;
    int lm = lane & 15, lq = lane >> 4;
    int wm = (w & 1) * 64, wn = (w >> 1) * 32;
    f32x4 acc[4][2];
#pragma unroll
    for (int mt = 0; mt < 4; ++mt)
#pragma unroll
        for (int nt = 0; nt < 2; ++nt) acc[mt][nt] = (f32x4){0.f, 0.f, 0.f, 0.f};
#pragma unroll
    for (int kb = 0; kb < 4; ++kb) {
        int ko = kb * 32 + lq * 8;
        bf16x8 b0 = *(const bf16x8*)(wt + (wn + lm) * XS + ko);
        bf16x8 b1 = *(const bf16x8*)(wt + (wn + 16 + lm) * XS + ko);
#pragma unroll
        for (int mt = 0; mt < 4; ++mt) {
            bf16x8 af = *(const bf16x8*)(xb + (wm + mt * 16 + lm) * XS + ko);
            acc[mt][0] = __builtin_amdgcn_mfma_f32_16x16x32_bf16(af, b0, acc[mt][0], 0, 0, 0);
            acc[mt][1] = __builtin_amdgcn_mfma_f32_16x16x32_bf16(af, b1, acc[mt][1], 0, 0, 0);
        }
    }
#pragma unroll
    for (int mt = 0; mt < 4; ++mt)
#pragma unroll
        for (int nt = 0; nt < 2; ++nt) {
            f32x4 a = acc[mt][nt];
            ushort4 pk;
            pk.x = f2bf(a[0]); pk.y = f2bf(a[1]); pk.z = f2bf(a[2]); pk.w = f2bf(a[3]);
            *(ushort4*)(hS + (wn + nt * 16 + lm) * XS + wm + mt * 16 + lq * 4) = pk;
        }
}

// mm2: xb[m=node][n=d] = silu(Ab[m][k] @ hS[n][k] + bias[n]) bf16
__device__ __forceinline__ void mm_agg(const unsigned short* __restrict__ Ab,
                                       const unsigned short* __restrict__ hS,
                                       unsigned short* __restrict__ xb,
                                       float bn0, float bn1, int tid) {
    int lane = tid & 63, w = tid >> 6;
    int lm = lane & 15, lq = lane >> 4;
    int wm = (w & 1) * 64, wn = (w >> 1) * 32;
    f32x4 acc[4][2];
#pragma unroll
    for (int mt = 0; mt < 4; ++mt)
#pragma unroll
        for (int nt = 0; nt < 2; ++nt) acc[mt][nt] = (f32x4){0.f, 0.f, 0.f, 0.f};
#pragma unroll
    for (int kb = 0; kb < 4; ++kb) {
        int ko = kb * 32 + lq * 8;
        bf16x8 b0 = *(const bf16x8*)(hS + (wn + lm) * XS + ko);
        bf16x8 b1 = *(const bf16x8*)(hS + (wn + 16 + lm) * XS + ko);
#pragma unroll
        for (int mt = 0; mt < 4; ++mt) {
            bf16x8 af = *(const bf16x8*)(Ab + (wm + mt * 16 + lm) * XS + ko);
            acc[mt][0] = __builtin_amdgcn_mfma_f32_16x16x32_bf16(af, b0, acc[mt][0], 0, 0, 0);
            acc[mt][1] = __builtin_amdgcn_mfma_f32_16x16x32_bf16(af, b1, acc[mt][1], 0, 0, 0);
        }
    }
#pragma unroll
    for (int mt = 0; mt < 4; ++mt)
#pragma unroll
        for (int nt = 0; nt < 2; ++nt) {
            float bn = nt ? bn1 : bn0;
            int col = wn + nt * 16 + lm;
#pragma unroll
            for (int i = 0; i < 4; ++i) {
                float v = silu_f(acc[mt][nt][i] + bn);
                xb[(wm + mt * 16 + lq * 4 + i) * XS + col] = f2bf(v);
            }
        }
}

__global__ __launch_bounds__(512) void gcn_kernel(
    const float* __restrict__ xg, const float* __restrict__ scale, const float* __restrict__ shift,
    const float* __restrict__ W1, const float* __restrict__ b1,
    const float* __restrict__ b2, const float* __restrict__ b3,
    const unsigned short* __restrict__ AbG,
    const unsigned short* __restrict__ Wt2g, const unsigned short* __restrict__ Wt3g,
    float* __restrict__ emb) {
    extern __shared__ char smem[];
    unsigned short* xb = (unsigned short*)smem;              // 34816 B  [node][d]
    unsigned short* hS = (unsigned short*)(smem + 34816);    // 34816 B  [d][node]
    unsigned short* Ab = (unsigned short*)(smem + 69632);    // 34816 B  [dst][src]
    unsigned short* wt = (unsigned short*)(smem + 104448);   // 34816 B  [dout][din]
    float* xinL  = (float*)(smem + 139264);                  // 354 f
    float* meanS = (float*)(smem + 140688);                  // 512 f (end 142736)
    int tid = threadIdx.x;
    int lane = tid & 63, w = tid >> 6;
    int g = blockIdx.x;

    for (int i = tid; i < 2176; i += 512) ((uint4*)hS)[i] = (uint4){0, 0, 0, 0};
    for (int i = tid; i < 170; i += 512) ((uint4*)(xb + NN * XS))[i] = (uint4){0, 0, 0, 0};
    float s0 = scale[0], s1 = scale[1], s2 = scale[2];
    float t0 = shift[0], t1 = shift[1], t2 = shift[2];
    const float* xrow = xg + (size_t)g * (NN * 3);
    for (int i = tid; i < NN * 3; i += 512) {
        int f = i % 3;
        float sc = (f == 0) ? s0 : ((f == 1) ? s1 : s2);
        float sf = (f == 0) ? t0 : ((f == 1) ? t1 : t2);
        xinL[i] = xrow[i] * sc + sf;
    }
    load_m(AbG, Ab, tid);
    load_m(Wt2g, wt, tid);
    int lm = lane & 15;
    int wn = (w >> 1) * 32;
    int n0 = wn + lm, n1 = wn + 16 + lm;
    float b1a = b1[n0], b1b = b1[n1];
    float b2a = b2[n0], b2b = b2[n1];
    float b3a = b3[n0], b3b = b3[n1];
    int dd = lane * 2;
    float2 w10 = *(const float2*)(W1 + dd);
    float2 w11 = *(const float2*)(W1 + DD + dd);
    float2 w12 = *(const float2*)(W1 + 2 * DD + dd);
    bar_lds();
    for (int k = 0; k < 15; ++k) {
        int n = w + 8 * k;
        if (n >= NN) break;
        float x0 = xinL[n * 3], x1 = xinL[n * 3 + 1], x2 = xinL[n * 3 + 2];
        hS[dd * XS + n]       = f2bf(x0 * w10.x + x1 * w11.x + x2 * w12.x);
        hS[(dd + 1) * XS + n] = f2bf(x0 * w10.y + x1 * w11.y + x2 * w12.y);
    }
    bar_lds();
    mm_agg(Ab, hS, xb, b1a, b1b, tid);   // x1
    bar_lds();
    mm_xw(xb, wt, hS, tid);              // h2
    bar_lds();
    load_m(Wt3g, wt, tid);
    mm_agg(Ab, hS, xb, b2a, b2b, tid);   // x2
    bar_lds();
    mm_xw(xb, wt, hS, tid);              // h3
    bar_lds();
    mm_agg(Ab, hS, xb, b3a, b3b, tid);   // x3
    bar_lds();
    {
        int d = tid & 127, part = tid >> 7;
        int a0 = part * 30;
        int a1 = (a0 + 30 < NN) ? (a0 + 30) : NN;
        float s = 0.f;
        for (int n = a0; n < a1; ++n) s += bf2f(xb[n * XS + d]);
        meanS[part * 128 + d] = s;
    }
    bar_lds();
    if (tid < 128) {
        float s = meanS[tid] + meanS[128 + tid] + meanS[256 + tid] + meanS[384 + tid];
        emb[(size_t)g * DD + tid] = s * (1.0f / (float)NN);
    }
}

// ---------------------------------------------------------------------------
// proj: dst[g][j] = bias[j] + sum_k src[g][k] * WT[k][j]
// ---------------------------------------------------------------------------
__global__ __launch_bounds__(512) void proj_kernel(const float* __restrict__ src,
                                                   const float* __restrict__ WT,
                                                   const float* __restrict__ bias,
                                                   float* __restrict__ dst) {
    __shared__ __align__(16) float eL[DD];
    int g = blockIdx.x, tid = threadIdx.x;
    if (tid < DD) eL[tid] = src[(size_t)g * DD + tid];
    __syncthreads();
    float acc = bias[tid];
    const float* wt = WT + tid;
#pragma unroll 8
    for (int k = 0; k < DD; ++k) acc += eL[k] * wt[(size_t)k * FD];
    dst[(size_t)g * FD + tid] = acc;
}

// ---------------------------------------------------------------------------
// LSTM scan: one block of 512 threads (8 waves) per batch element.
// K-split 4: thread (quarter, d) owns all 4 gate rows of dim d over
// K in [32*quarter, +32) -> 64 weight regs/thread (no AGPR parking possible;
// round 9 at 128 regs paid ~256 cyc/step of accvgpr reads; round 8 at 256
// spilled outright). asm-pinned SCALARS (uint4 field pins failed, round 10).
// Per step: 4 broadcast ds_read_b128/lane, quarters 1-3 write one float4
// partial, quarter 0 sums + x + activations + lane-local c/h. 2 barriers.
// ---------------------------------------------------------------------------
__global__ __launch_bounds__(512, 2) void scan_kernel(
    const float* __restrict__ inp,          // [B][T][512] gate-major (bias incl)
    const unsigned int* __restrict__ Wc,    // [(g*16+q)*4+quarter][d] f16 pairs
    float* __restrict__ hout, int full) {
    __shared__ __align__(16) unsigned short hL[DD];  // h as f16
    __shared__ __align__(16) float sgP[3 * DD * 4];  // quarters 1-3 partials
    int b = blockIdx.x, j = threadIdx.x;
    int d = j & 127, quarter = j >> 7;
    unsigned int wreg[4][16];
#pragma unroll
    for (int g = 0; g < 4; ++g)
#pragma unroll
        for (int q = 0; q < 16; ++q)
            wreg[g][q] = Wc[(((g * 16 + q) << 2) + quarter) * 128 + d];
    // pin scalars: asm-defined values cannot be rematerialized into the loop
#pragma unroll
    for (int g = 0; g < 4; ++g)
#pragma unroll
        for (int q = 0; q < 16; ++q)
            asm volatile("" : "+v"(wreg[g][q]));
    if (j < 64) ((unsigned int*)hL)[j] = 0u;
    float creg = 0.f;
    const float* ib = inp + (size_t)b * TT * FD;
    float* hb_ = hout + (size_t)b * (full ? TT * DD : DD);
    float xg0[4], xg1[4];
    if (quarter == 0) {
#pragma unroll
        for (int g = 0; g < 4; ++g) { xg0[g] = ib[g * DD + d]; xg1[g] = ib[FD + g * DD + d]; }
    }
    bar_lds();
    for (int t = 0; t < TT; ++t) {
        float xg2[4];
        if (quarter == 0) {
            bool more = (t + 2 < TT);
#pragma unroll
            for (int g = 0; g < 4; ++g)
                xg2[g] = more ? ib[(t + 2) * FD + g * DD + d] : 0.f;  // prefetch depth 2
        }
        const uint4* h4 = (const uint4*)(hL + quarter * 32);  // 4 chunks, wave-uniform
        float a0 = 0.f, a1 = 0.f, a2 = 0.f, a3 = 0.f;
#pragma unroll
        for (int c = 0; c < 4; ++c) {
            uint4 hv = h4[c];
            a0 = fdot2_(wreg[0][4 * c + 0], hv.x, a0);
            a1 = fdot2_(wreg[1][4 * c + 0], hv.x, a1);
            a2 = fdot2_(wreg[2][4 * c + 0], hv.x, a2);
            a3 = fdot2_(wreg[3][4 * c + 0], hv.x, a3);
            a0 = fdot2_(wreg[0][4 * c + 1], hv.y, a0);
            a1 = fdot2_(wreg[1][4 * c + 1], hv.y, a1);
            a2 = fdot2_(wreg[2][4 * c + 1], hv.y, a2);
            a3 = fdot2_(wreg[3][4 * c + 1], hv.y, a3);
            a0 = fdot2_(wreg[0][4 * c + 2], hv.z, a0);
            a1 = fdot2_(wreg[1][4 * c + 2], hv.z, a1);
            a2 = fdot2_(wreg[2][4 * c + 2], hv.z, a2);
            a3 = fdot2_(wreg[3][4 * c + 2], hv.z, a3);
            a0 = fdot2_(wreg[0][4 * c + 3], hv.w, a0);
            a1 = fdot2_(wreg[1][4 * c + 3], hv.w, a1);
            a2 = fdot2_(wreg[2][4 * c + 3], hv.w, a2);
            a3 = fdot2_(wreg[3][4 * c + 3], hv.w, a3);
        }
        if (quarter != 0)
            *(float4*)(sgP + ((quarter - 1) * DD + d) * 4) = make_float4(a0, a1, a2, a3);
        bar_lds();
        if (quarter == 0) {
            float4 p1 = *(const float4*)(sgP + d * 4);
            float4 p2 = *(const float4*)(sgP + (DD + d) * 4);
            float4 p3 = *(const float4*)(sgP + (2 * DD + d) * 4);
            float iv = sig_f(a0 + p1.x + p2.x + p3.x + xg0[0]);
            float fv = sig_f(a1 + p1.y + p2.y + p3.y + xg0[1]);
            float gv = tanh_f(a2 + p1.z + p2.z + p3.z + xg0[2]);
            float ov = sig_f(a3 + p1.w + p2.w + p3.w + xg0[3]);
            float cn = fv * creg + iv * gv;
            creg = cn;
            float hn = ov * tanh_f(cn);
            ((_Float16*)hL)[d] = (_Float16)hn;
            if (full) hb_[t * DD + d] = hn;           // fire-and-forget
            else if (t == TT - 1) hb_[d] = hn;
#pragma unroll
            for (int g = 0; g < 4; ++g) { xg0[g] = xg1[g]; xg1[g] = xg2[g]; }
        }
        bar_lds();
    }
}

// ---------------------------------------------------------------------------
// head MLP on final hidden state. 1 block.
// ---------------------------------------------------------------------------
__global__ void head_kernel(const float* __restrict__ hfin,
                            const float* __restrict__ hW1, const float* __restrict__ hb1,
                            const float* __restrict__ hW2, const float* __restrict__ hb2,
                            const float* __restrict__ hW3, const float* __restrict__ hb3,
                            float* __restrict__ out) {
    __shared__ float fh[BB * DD];
    __shared__ float y1[BB * DD];
    __shared__ float y2[BB * 64];
    int tid = threadIdx.x;
    for (int i = tid; i < BB * DD; i += 256) fh[i] = hfin[i];
    __syncthreads();
    for (int i = tid; i < BB * DD; i += 256) {
        int bb = i >> 7, jj = i & 127;
        float acc = hb1[jj];
        for (int k = 0; k < DD; ++k) acc += fh[(bb << 7) + k] * hW1[(k << 7) + jj];
        y1[i] = siluf_(acc);
    }
    __syncthreads();
    for (int i = tid; i < BB * 64; i += 256) {
        int bb = i >> 6, jj = i & 63;
        float acc = hb2[jj];
        for (int k = 0; k < DD; ++k) acc += y1[(bb << 7) + k] * hW2[(k << 6) + jj];
        y2[i] = siluf_(acc);
    }
    __syncthreads();
    if (tid < BB * 2) {
        int bb = tid >> 1, m = tid & 1;
        float acc = hb3[m];
        for (int k = 0; k < 64; ++k) acc += y2[(bb << 6) + k] * hW3[k * 2 + m];
        float sp = fmaxf(acc, 0.f) + log1pf(expf(-fabsf(acc)));
        out[tid] = sp + 1e-6f;
    }
}

// ---------------------------------------------------------------------------
extern "C" void kernel_launch(void* const* d_in, const int* in_sizes, int n_in,
                              void* d_out, int out_size, void* d_ws, size_t ws_size,
                              hipStream_t stream) {
    const float* snap  = (const float*)d_in[0];
    const int*   edges = (const int*)d_in[1];
    const float* scale = (const float*)d_in[2];
    const float* shift = (const float*)d_in[3];
    const float* W1 = (const float*)d_in[4];
    const float* b1 = (const float*)d_in[5];
    const float* W2 = (const float*)d_in[6];
    const float* b2 = (const float*)d_in[7];
    const float* W3 = (const float*)d_in[8];
    const float* b3 = (const float*)d_in[9];
    const float* Wih0 = (const float*)d_in[10];
    const float* Whh0 = (const float*)d_in[11];
    const float* bih0 = (const float*)d_in[12];
    const float* bhh0 = (const float*)d_in[13];
    const float* Wih1 = (const float*)d_in[14];
    const float* Whh1 = (const float*)d_in[15];
    const float* bih1 = (const float*)d_in[16];
    const float* bhh1 = (const float*)d_in[17];
    const float* hW1 = (const float*)d_in[18];
    const float* hb1 = (const float*)d_in[19];
    const float* hW2 = (const float*)d_in[20];
    const float* hb2 = (const float*)d_in[21];
    const float* hW3 = (const float*)d_in[22];
    const float* hb3 = (const float*)d_in[23];

    // workspace carve (float indices); ~7.2 MB
    float* ws = (float*)d_ws;
    float* bias0 = ws + 0;                        // 512
    float* bias1 = ws + 512;                      // 512
    unsigned short* AbG  = (unsigned short*)(ws + 1024);   // 8192 f
    unsigned short* Wt2g = (unsigned short*)(ws + 9216);   // 8192 f
    unsigned short* Wt3g = (unsigned short*)(ws + 17408);  // 8192 f
    float* WT0 = ws + 25600;                      // 65536
    float* WT1 = ws + 91136;                      // 65536
    unsigned int* Wc0 = (unsigned int*)(ws + 156672);      // 32768
    unsigned int* Wc1 = (unsigned int*)(ws + 189440);      // 32768
    float* emb   = ws + 222208;                   // 262144
    float* inp   = ws + 484352;                   // 1048576 (both LSTM layers)
    float* h0seq = ws + 1532928;                  // 262144
    float* hfin  = ws + 1795072;                  // 1024

    const int smem_gcn = 142736;
    hipFuncSetAttribute((const void*)gcn_kernel,
                        hipFuncAttributeMaxDynamicSharedMemorySize, smem_gcn);

    prep_kernel<<<1, 256, 0, stream>>>(edges, bih0, bhh0, bih1, bhh1,
                                       bias0, bias1, AbG);
    convw_kernel<<<32, 512, 0, stream>>>(W2, Wt2g);
    convw_kernel<<<32, 512, 0, stream>>>(W3, Wt3g);
    convh_kernel<<<64, 512, 0, stream>>>(Whh0, Wc0);
    convh_kernel<<<64, 512, 0, stream>>>(Whh1, Wc1);
    transpose_kernel<<<128, 512, 0, stream>>>(Wih0, WT0);
    transpose_kernel<<<128, 512, 0, stream>>>(Wih1, WT1);
    gcn_kernel<<<GG, 512, smem_gcn, stream>>>(snap, scale, shift, W1, b1, b2, b3,
                                              AbG, Wt2g, Wt3g, emb);
    proj_kernel<<<GG, 512, 0, stream>>>(emb, WT0, bias0, inp);
    scan_kernel<<<BB, 512, 0, stream>>>(inp, Wc0, h0seq, 1);
    proj_kernel<<<GG, 512, 0, stream>>>(h0seq, WT1, bias1, inp);
    scan_kernel<<<BB, 512, 0, stream>>>(inp, Wc1, hfin, 0);
    head_kernel<<<1, 256, 0, stream>>>(hfin, hW1, hb1, hW2, hb2, hW3, hb3, (float*)d_out);
}